// Round 16
// baseline (69.819 us; speedup 1.0000x reference)
//
#include <hip/hip_runtime.h>
#include <math.h>

typedef __attribute__((ext_vector_type(8))) __bf16 b16x8;
typedef __attribute__((ext_vector_type(16))) float f32x16;

__device__ __forceinline__ unsigned short f2bf(float x) {
    unsigned int v = __float_as_uint(x);
    v += 0x7fffu + ((v >> 16) & 1u);
    return (unsigned short)(v >> 16);
}

// ---------------- repack kernel ----------------
// ws: [0, 819200): weights bf16 as 32x32x16 A-fragments, visit order:
//   slot l = kw*10 + ks*5 + kh  (conv tap = kh*5+kw, cin plane ks)
//   byte = l*16384 + wn*2048 + kseg*1024 + lane*16
//   value = W[cin = ks*32 + kseg*16 + (lane>>5)*8 + j][o = wn*32 + (lane&31)]
//   (A-frag layout: m = lane&31 = od, k = (lane>>5)*8 + j)
// [819200, 820224): bias_sum fp32 [256]
__global__ __launch_bounds__(256) void repack_w(
    const float* __restrict__ Wt, const float* __restrict__ bias,
    unsigned short* __restrict__ wsw, float* __restrict__ wsb) {
    int idx = blockIdx.x * 256 + threadIdx.x;
    if (idx < 409600) {
        int j    = idx & 7;
        int lane = (idx >> 3) & 63;
        int kseg = (idx >> 9) & 1;
        int wn   = (idx >> 10) & 7;
        int l    = idx >> 13;          // visit slot 0..49
        int kh   = l % 5;
        int ks   = (l / 5) & 1;
        int kw   = l / 10;
        int tap  = kh * 5 + kw;
        int o    = wn * 32 + (lane & 31);
        int cin  = ks * 32 + kseg * 16 + (lane >> 5) * 8 + j;
        int ic = cin >> 4, id = cin & 15;
        float w = Wt[((size_t)(ic * 256 + o) * 16 + id) * 25 + tap];
        wsw[idx] = f2bf(w);
    } else if (idx < 409856) {
        int o = idx - 409600;
        float s = 0.f;
        for (int ic = 0; ic < 4; ++ic) s += bias[ic * 256 + o];
        wsb[o] = s;
    }
}

// ---------------- main kernel ----------------
// R15 structure (16 waves, 16x16 tile, zero barriers after prologue, swapped
// operands, dist-2 weight prefetch) with MFMA shape 32x32x16:
//  - Wave = 8 px-rows x 32 od. 4 C-tiles: tile t = px-columns {(y=ybase+t+
//    4*(n>>4), x=n&15) : n=0..31} (stride-4 row pairing). B-frag(t,kh) ==
//    frag s=t+kh -> 4-deep circular window per kseg, 1 slide/kh.
//  - 8 MFMA/slot/wave (vs 16), ~13% less matrix-pipe time (m119), half the
//    issue slots. acc = 4 x f32x16.
//  - Squash: od = (reg&3)+8*(reg>>2)+4*(lane>>5): 16 in-lane + shfl_xor(32).
__global__ __launch_bounds__(1024, 4) void caps_mfma(
    const float* __restrict__ u, const unsigned short* __restrict__ wsw,
    const float* __restrict__ wsb, float* __restrict__ out) {

    __shared__ __align__(16) unsigned short su_sh[25600];   // 2 planes x [hy20][hx20][cgp4][j8]

    const int tid  = threadIdx.x;
    const int lane = tid & 63;
    const int wid  = tid >> 6;      // 0..15
    const int wm   = wid >> 3;      // 0..1  pixel-row-group (8 rows each)
    const int wn   = wid & 7;       // 0..7  capsule (32 outs each)
    const int n31  = lane & 31;     // B/C column index
    const int hi   = lane >> 5;     // K-half selector
    const int xl   = n31 & 15;      // pixel x within tile
    const int ybase = wm * 8;
    // lane's row base: rows ybase+s (n31<16) / ybase+s+4 (n31>=16)
    const int ybw  = ybase + (n31 >> 4) * 4;

    const int bx  = blockIdx.x;     // 0..63
    const int b   = blockIdx.y;     // 0..3
    const int ty0 = (bx >> 3) * 16;
    const int tx0 = (bx & 7) * 16;

    f32x16 acc[4];
    #pragma unroll
    for (int t = 0; t < 4; ++t) acc[t] = (f32x16)0.f;

    auto stage_u = [&](int half) {
        const float* up = u + ((size_t)b * 64 + half * 32) * 16384;
        unsigned short* dstp = su_sh + half * 12800;
        #pragma unroll 1
        for (int i = tid; i < 12800; i += 1024) {
            int c = i / 400;                    // cin local 0..31
            int s = i - c * 400;
            int hy = s / 20, hx = s - hy * 20;  // halo coords 0..19
            int gy = ty0 - 2 + hy, gx = tx0 - 2 + hx;
            float v = 0.f;
            if ((unsigned)gy < 128u && (unsigned)gx < 128u)
                v = up[(size_t)c * 16384 + gy * 128 + gx];
            int cgp = (c >> 3) ^ ((hx >> 1) & 3);
            dstp[(hy * 20 + hx) * 32 + cgp * 8 + (c & 7)] = f2bf(v);
        }
    };

    // per-wave weight base: slot stride 16384B, [wn]2048B, [kseg]1024B, lane*16B
    const char* wp0 = ((const char*)wsw) + wn * 2048 + lane * 16;

    // W triple buffer (distance-2 prefetch), rotated at compile time
    b16x8 wf[3][2];
    #define LOADA(SLOT, BUF)                                                   \
        {                                                                      \
            const char* p_ = wp0 + (size_t)((SLOT) > 49 ? 49 : (SLOT)) * 16384;\
            wf[BUF][0] = *reinterpret_cast<const b16x8*>(p_);                  \
            wf[BUF][1] = *reinterpret_cast<const b16x8*>(p_ + 1024);           \
        }

    // prologue
    LOADA(0, 0)
    LOADA(1, 1)
    stage_u(0);
    stage_u(1);
    __syncthreads();               // su_sh stable from here on; no more barriers

    #pragma unroll
    for (int g = 0; g < 5; ++g) {                  // g == kw (fully unrolled)
        const int hxl  = xl + g;
        const int xorb = (hxl >> 1) & 3;
        const int off0 = ybw * 640 + hxl * 32 + ((hi ^ xorb) * 8);       // kseg 0
        const int off1 = ybw * 640 + hxl * 32 + (((2 + hi) ^ xorb) * 8); // kseg 1
        #pragma unroll
        for (int ks = 0; ks < 2; ++ks) {
            const unsigned short* base0 = su_sh + ks * 12800 + off0;
            const unsigned short* base1 = su_sh + ks * 12800 + off1;

            // init circular B-window: frags s=0..3 per kseg
            b16x8 aw0[4], aw1[4];
            #pragma unroll
            for (int i = 0; i < 4; ++i) {
                aw0[i] = *reinterpret_cast<const b16x8*>(base0 + i * 640);
                aw1[i] = *reinterpret_cast<const b16x8*>(base1 + i * 640);
            }

            #pragma unroll
            for (int kh = 0; kh < 5; ++kh) {
                const int l = g * 10 + ks * 5 + kh;     // compile-time

                LOADA(l + 2, (l + 2) % 3)               // distance-2 prefetch

                __builtin_amdgcn_s_setprio(1);
                #pragma unroll
                for (int t = 0; t < 4; ++t) {
                    // A = weights (m=od), B = u frag s=kh+t (n=pixel)
                    acc[t] = __builtin_amdgcn_mfma_f32_32x32x16_bf16(
                        wf[l % 3][0], aw0[(kh + t) & 3], acc[t], 0, 0, 0);
                    acc[t] = __builtin_amdgcn_mfma_f32_32x32x16_bf16(
                        wf[l % 3][1], aw1[(kh + t) & 3], acc[t], 0, 0, 0);
                }
                __builtin_amdgcn_s_setprio(0);

                if (kh < 4) {                           // slide AFTER cluster:
                    aw0[kh & 3] = *reinterpret_cast<const b16x8*>(
                        base0 + (kh + 4) * 640);        // frag s=kh+4
                    aw1[kh & 3] = *reinterpret_cast<const b16x8*>(
                        base1 + (kh + 4) * 640);
                }
            }
        }
    }
    #undef LOADA

    // ---- epilogue: bias + r-scale + squash (in-lane + 1 shfl) + stores ----
    // C layout: col n=lane&31 -> (y = ty0+ybase+t+4*(n>>4), x = tx0+(n&15));
    // row = od = (reg&3) + 8*(reg>>2) + 4*hi.
    float4 bb[4];
    #pragma unroll
    for (int q = 0; q < 4; ++q)
        bb[q] = *reinterpret_cast<const float4*>(wsb + wn * 32 + q * 8 + hi * 4);

    const int x = tx0 + xl;
    const int colsv = min(x + 2, 127) - max(x - 2, 0) + 1;
    float* pout = out + ((size_t)(b * 8 + wn) * 32 + 4 * hi) * 16384 + x;

    #pragma unroll
    for (int t = 0; t < 4; ++t) {
        int y = ty0 + ybw + t;
        int rows = min(y + 2, 127) - max(y - 2, 0) + 1;
        float rs = 1.0f / (8.0f * (float)(rows * colsv));
        float p[16];
        float sq = 0.f;
        #pragma unroll
        for (int q = 0; q < 4; ++q)
            #pragma unroll
            for (int r = 0; r < 4; ++r) {
                float v = (acc[t][q * 4 + r] + bb[q][r]) * rs;
                p[q * 4 + r] = v;
                sq += v * v;
            }
        sq += __shfl_xor(sq, 32);       // partner holds the other 16 od
        float scale = sq / ((1.0f + sq) * sqrtf(sq + 1e-9f));
        float* ph = pout + (size_t)y * 128;
        #pragma unroll
        for (int q = 0; q < 4; ++q)
            #pragma unroll
            for (int r = 0; r < 4; ++r)
                ph[(size_t)(q * 8 + r) * 16384] = p[q * 4 + r] * scale;
    }
}

extern "C" void kernel_launch(void* const* d_in, const int* in_sizes, int n_in,
                              void* d_out, int out_size, void* d_ws, size_t ws_size,
                              hipStream_t stream) {
    const float* u    = (const float*)d_in[0];
    const float* Wt   = (const float*)d_in[1];
    const float* bias = (const float*)d_in[2];
    unsigned short* wsw = (unsigned short*)d_ws;
    float* wsb = (float*)((char*)d_ws + 819200);

    repack_w<<<1601, 256, 0, stream>>>(Wt, bias, wsw, wsb);
    caps_mfma<<<dim3(64, 4), 1024, 0, stream>>>(u, wsw, wsb, (float*)d_out);
}

// Round 17
// 66.283 us; speedup vs baseline: 1.0533x; 1.0533x over previous
//
#include <hip/hip_runtime.h>
#include <math.h>

typedef __attribute__((ext_vector_type(8))) __bf16 b16x8;
typedef __attribute__((ext_vector_type(4))) float f32x4;

__device__ __forceinline__ unsigned short f2bf(float x) {
    unsigned int v = __float_as_uint(x);
    v += 0x7fffu + ((v >> 16) & 1u);
    return (unsigned short)(v >> 16);
}

// ---------------- repack kernel ---------------- (layout identical to R15)
// ws: [0, 819200): weights bf16, PER-WAVE-CONTIGUOUS, visit order:
//   slot l = kw*10 + ks*5 + kh   (conv tap = kh*5+kw, cin plane ks)
//   byte = l*16384 + cap*2048 + fr*1024 + lane*16     (cap = capsule 0..7)
//   value = W[cin = ks*32 + (lane>>4)*8 + j][o = cap*32 + fr*16 + (lane&15)]
// [819200, 820224): bias_sum fp32 [256]
__global__ __launch_bounds__(256) void repack_w(
    const float* __restrict__ Wt, const float* __restrict__ bias,
    unsigned short* __restrict__ wsw, float* __restrict__ wsb) {
    int idx = blockIdx.x * 256 + threadIdx.x;
    if (idx < 409600) {
        int j    = idx & 7;
        int lane = (idx >> 3) & 63;
        int fr   = (idx >> 9) & 1;
        int wn   = (idx >> 10) & 7;
        int l    = idx >> 13;          // visit slot 0..49
        int kh   = l % 5;
        int ks   = (l / 5) & 1;
        int kw   = l / 10;
        int tap  = kh * 5 + kw;
        int col  = lane & 15;
        int cg   = lane >> 4;
        int o    = wn * 32 + fr * 16 + col;
        int cin  = ks * 32 + cg * 8 + j;
        int ic = cin >> 4, id = cin & 15;
        float w = Wt[((size_t)(ic * 256 + o) * 16 + id) * 25 + tap];
        wsw[idx] = f2bf(w);
    } else if (idx < 409856) {
        int o = idx - 409600;
        float s = 0.f;
        for (int ic = 0; ic < 4; ++ic) s += bias[ic * 256 + o];
        wsb[o] = s;
    }
}

// ---------------- main kernel ----------------
// R15's exact per-wave loop (128px x 32out wave, swapped MFMA operands,
// dist-2 triple-buffer weight prefetch, circular A-window, zero barriers
// after prologue), re-decomposed for 2 BLOCKS/CU:
//   block = 512 threads (8 waves) = one 16x16 tile x 128 outs (4 capsules).
//   grid = 128 x 4 = 512 blocks = 2/CU (VGPR ~64, LDS 51.2KB x2 = 102.4KB).
// The co-resident block's prologue (halo stage) and epilogue (64MB store
// burst) overlap this block's MFMA loop -> the previously-serial ~14us of
// tails hide under compute.
// XCD pairing: halves of a tile sit at bx and bx+8 -> same dispatch%8 ->
// same XCD (m09 round-robin) -> second halo stage hits that XCD's L2.
__global__ __launch_bounds__(512, 4) void caps_mfma(
    const float* __restrict__ u, const unsigned short* __restrict__ wsw,
    const float* __restrict__ wsb, float* __restrict__ out) {

    __shared__ __align__(16) unsigned short su_sh[25600];   // 2 planes x [hy20][hx20][cgp4][j8]

    const int tid  = threadIdx.x;
    const int lane = tid & 63;
    const int wid  = tid >> 6;      // 0..7
    const int wm   = wid >> 2;      // 0..1  pixel-row-group (8 rows each)
    const int wn   = wid & 3;       // 0..3  capsule-within-half
    const int col  = lane & 15;
    const int xg   = lane >> 4;     // 0..3
    const int ybase = wm * 8;

    const int bx  = blockIdx.x;     // 0..127
    const int b   = blockIdx.y;     // 0..3
    const int tg   = ((bx >> 4) << 3) | (bx & 7);   // tile 0..63
    const int half = (bx >> 3) & 1;                 // capsule half
    const int cap  = half * 4 + wn;                 // capsule 0..7
    const int ty0 = (tg >> 3) * 16;
    const int tx0 = (tg & 7) * 16;

    f32x4 acc[8][2];
    #pragma unroll
    for (int f = 0; f < 8; ++f) {
        acc[f][0] = (f32x4)0.f;
        acc[f][1] = (f32x4)0.f;
    }

    auto stage_u = [&](int h2) {
        const float* up = u + ((size_t)b * 64 + h2 * 32) * 16384;
        unsigned short* dstp = su_sh + h2 * 12800;
        #pragma unroll 1
        for (int i = tid; i < 12800; i += 512) {
            int c = i / 400;                    // cin local 0..31
            int s = i - c * 400;
            int hy = s / 20, hx = s - hy * 20;  // halo coords 0..19
            int gy = ty0 - 2 + hy, gx = tx0 - 2 + hx;
            float v = 0.f;
            if ((unsigned)gy < 128u && (unsigned)gx < 128u)
                v = up[(size_t)c * 16384 + gy * 128 + gx];
            int cgp = (c >> 3) ^ ((hx >> 1) & 3);
            dstp[(hy * 20 + hx) * 32 + cgp * 8 + (c & 7)] = f2bf(v);
        }
    };

    // per-wave weight base: slot stride 16384B, [cap]2048B, [fr]1024B, lane*16B
    const char* wp0 = ((const char*)wsw) + cap * 2048 + lane * 16;

    // B triple buffer (distance-2 prefetch), rotated at compile time
    b16x8 bf[3][2];
    #define LOADB(SLOT, BUF)                                                   \
        {                                                                      \
            const char* p_ = wp0 + (size_t)((SLOT) > 49 ? 49 : (SLOT)) * 16384;\
            bf[BUF][0] = *reinterpret_cast<const b16x8*>(p_);                  \
            bf[BUF][1] = *reinterpret_cast<const b16x8*>(p_ + 1024);           \
        }

    // prologue
    LOADB(0, 0)
    LOADB(1, 1)
    stage_u(0);
    stage_u(1);
    __syncthreads();               // su_sh stable from here on; no more barriers

    #pragma unroll
    for (int g = 0; g < 5; ++g) {                  // g == kw (fully unrolled)
        const int hx   = col + g;
        const int coff = hx * 32 + ((xg ^ ((hx >> 1) & 3)) * 8);
        #pragma unroll
        for (int ks = 0; ks < 2; ++ks) {
            const unsigned short* apb =
                su_sh + ks * 12800 + ybase * 640 + coff;

            // init circular A-window (u-frags): rows 0..7 relative to ybase
            b16x8 aw[8];
            #pragma unroll
            for (int i = 0; i < 8; ++i)
                aw[i] = *reinterpret_cast<const b16x8*>(apb + i * 640);

            #pragma unroll
            for (int kh = 0; kh < 5; ++kh) {
                const int l = g * 10 + ks * 5 + kh;     // compile-time

                LOADB(l + 2, (l + 2) % 3)               // distance-2 prefetch

                __builtin_amdgcn_s_setprio(1);
                #pragma unroll
                for (int f = 0; f < 8; ++f) {
                    // SWAPPED: A = weights (lane&15 = od), B = u (lane&15 = x)
                    acc[f][0] = __builtin_amdgcn_mfma_f32_16x16x32_bf16(
                        bf[l % 3][0], aw[(kh + f) & 7], acc[f][0], 0, 0, 0);
                    acc[f][1] = __builtin_amdgcn_mfma_f32_16x16x32_bf16(
                        bf[l % 3][1], aw[(kh + f) & 7], acc[f][1], 0, 0, 0);
                }
                __builtin_amdgcn_s_setprio(0);

                if (kh < 4)                             // slide AFTER cluster
                    aw[kh & 7] = *reinterpret_cast<const b16x8*>(
                        apb + (kh + 8) * 640);
            }
        }
    }
    #undef LOADB

    // ---- epilogue: bias + r-scale + squash (in-lane + 2 shfl) + stores ----
    // C layout: value(y=ybase+f, x=tx0+col, od=fr*16+xg*4+r)
    float4 bb0 = *reinterpret_cast<const float4*>(wsb + cap * 32 + xg * 4);
    float4 bb1 = *reinterpret_cast<const float4*>(wsb + cap * 32 + 16 + xg * 4);

    const int x = tx0 + col;
    const int colsv = min(x + 2, 127) - max(x - 2, 0) + 1;
    float* pout = out + ((size_t)(b * 8 + cap) * 32 + xg * 4) * 16384 + x;

    #pragma unroll
    for (int f = 0; f < 8; ++f) {
        int h = ty0 + ybase + f;
        int rows = min(h + 2, 127) - max(h - 2, 0) + 1;
        float rs = 1.0f / (8.0f * (float)(rows * colsv));
        float p[8];
        float sq = 0.f;
        #pragma unroll
        for (int r = 0; r < 4; ++r) {
            float v0 = (acc[f][0][r] + bb0[r]) * rs;
            float v1 = (acc[f][1][r] + bb1[r]) * rs;
            p[r] = v0; p[4 + r] = v1;
            sq += v0 * v0;
            sq += v1 * v1;
        }
        sq += __shfl_xor(sq, 16);
        sq += __shfl_xor(sq, 32);
        float scale = sq / ((1.0f + sq) * sqrtf(sq + 1e-9f));
        float* ph = pout + (size_t)h * 128;
        #pragma unroll
        for (int r = 0; r < 4; ++r) {
            ph[(size_t)r * 16384]        = p[r] * scale;      // od = xg*4+r
            ph[(size_t)(16 + r) * 16384] = p[4 + r] * scale;  // od = 16+xg*4+r
        }
    }
}

extern "C" void kernel_launch(void* const* d_in, const int* in_sizes, int n_in,
                              void* d_out, int out_size, void* d_ws, size_t ws_size,
                              hipStream_t stream) {
    const float* u    = (const float*)d_in[0];
    const float* Wt   = (const float*)d_in[1];
    const float* bias = (const float*)d_in[2];
    unsigned short* wsw = (unsigned short*)d_ws;
    float* wsb = (float*)((char*)d_ws + 819200);

    repack_w<<<1601, 256, 0, stream>>>(Wt, bias, wsw, wsb);
    caps_mfma<<<dim3(128, 4), 512, 0, stream>>>(u, wsw, wsb, (float*)d_out);
}

// Round 18
// 59.012 us; speedup vs baseline: 1.1831x; 1.1232x over previous
//
#include <hip/hip_runtime.h>
#include <math.h>

typedef __attribute__((ext_vector_type(8))) __bf16 b16x8;
typedef __attribute__((ext_vector_type(4))) float f32x4;

__device__ __forceinline__ unsigned short f2bf(float x) {
    unsigned int v = __float_as_uint(x);
    v += 0x7fffu + ((v >> 16) & 1u);
    return (unsigned short)(v >> 16);
}

// ---------------- repack kernel ----------------
// ws: [0, 819200): weights bf16, PER-WAVE-CONTIGUOUS, visit order:
//   slot l = kw*10 + ks*5 + kh   (conv tap = kh*5+kw, cin plane ks)
//   byte = l*16384 + wn*2048 + fr*1024 + lane*16
//   value = W[cin = ks*32 + (lane>>4)*8 + j][o = wn*32 + fr*16 + (lane&15)]
// [819200, 820224): bias_sum fp32 [256]
__global__ __launch_bounds__(256) void repack_w(
    const float* __restrict__ Wt, const float* __restrict__ bias,
    unsigned short* __restrict__ wsw, float* __restrict__ wsb) {
    int idx = blockIdx.x * 256 + threadIdx.x;
    if (idx < 409600) {
        int j    = idx & 7;
        int lane = (idx >> 3) & 63;
        int fr   = (idx >> 9) & 1;
        int wn   = (idx >> 10) & 7;
        int l    = idx >> 13;          // visit slot 0..49
        int kh   = l % 5;
        int ks   = (l / 5) & 1;
        int kw   = l / 10;
        int tap  = kh * 5 + kw;
        int col  = lane & 15;
        int cg   = lane >> 4;
        int o    = wn * 32 + fr * 16 + col;
        int cin  = ks * 32 + cg * 8 + j;
        int ic = cin >> 4, id = cin & 15;
        float w = Wt[((size_t)(ic * 256 + o) * 16 + id) * 25 + tap];
        wsw[idx] = f2bf(w);
    } else if (idx < 409856) {
        int o = idx - 409600;
        float s = 0.f;
        for (int ic = 0; ic < 4; ++ic) s += bias[ic * 256 + o];
        wsb[o] = s;
    }
}

// ---------------- main kernel ---------------- (R15, best verified: 59.1us)
// Block: 1024 threads (16 waves) = one 16x16 spatial tile x all 256 outputs;
// grid 64x4 = 256 blocks = 1/CU. Wave = 128px x 32out, zero barriers after
// the prologue.
//  - SWAPPED MFMA operands: acc = mfma(W_frag, u_frag, acc) -> C col = pixel
//    x, row = od; squash = 8 in-lane + shfl_xor(16)+shfl_xor(32); stores
//    contiguous per xg group.
//  - B (weights): distance-2 register prefetch, 3 buffers, compile-time %3
//    rotation (g-loop fully unrolled), straight from L2 (2KB/wave/slot).
//  - A (u): circular 8-row register window per (kw,ks); slide AFTER the
//    MFMA cluster (post-cluster write keeps the live row intact).
__global__ __launch_bounds__(1024, 4) void caps_mfma(
    const float* __restrict__ u, const unsigned short* __restrict__ wsw,
    const float* __restrict__ wsb, float* __restrict__ out) {

    __shared__ __align__(16) unsigned short su_sh[25600];   // 2 planes x [hy20][hx20][cgp4][j8]

    const int tid  = threadIdx.x;
    const int lane = tid & 63;
    const int wid  = tid >> 6;      // 0..15
    const int wm   = wid >> 3;      // 0..1  pixel-row-group (8 rows each)
    const int wn   = wid & 7;       // 0..7  capsule (32 outs each)
    const int col  = lane & 15;
    const int xg   = lane >> 4;     // 0..3
    const int ybase = wm * 8;

    const int bx  = blockIdx.x;     // 0..63
    const int b   = blockIdx.y;     // 0..3
    const int ty0 = (bx >> 3) * 16;
    const int tx0 = (bx & 7) * 16;

    f32x4 acc[8][2];
    #pragma unroll
    for (int f = 0; f < 8; ++f) {
        acc[f][0] = (f32x4)0.f;
        acc[f][1] = (f32x4)0.f;
    }

    auto stage_u = [&](int half) {
        const float* up = u + ((size_t)b * 64 + half * 32) * 16384;
        unsigned short* dstp = su_sh + half * 12800;
        #pragma unroll 1
        for (int i = tid; i < 12800; i += 1024) {
            int c = i / 400;                    // cin local 0..31
            int s = i - c * 400;
            int hy = s / 20, hx = s - hy * 20;  // halo coords 0..19
            int gy = ty0 - 2 + hy, gx = tx0 - 2 + hx;
            float v = 0.f;
            if ((unsigned)gy < 128u && (unsigned)gx < 128u)
                v = up[(size_t)c * 16384 + gy * 128 + gx];
            int cgp = (c >> 3) ^ ((hx >> 1) & 3);
            dstp[(hy * 20 + hx) * 32 + cgp * 8 + (c & 7)] = f2bf(v);
        }
    };

    // per-wave weight base: slot stride 16384B, [wn]2048B, [fr]1024B, lane*16B
    const char* wp0 = ((const char*)wsw) + wn * 2048 + lane * 16;

    // B triple buffer (distance-2 prefetch), rotated at compile time
    b16x8 bf[3][2];
    #define LOADB(SLOT, BUF)                                                   \
        {                                                                      \
            const char* p_ = wp0 + (size_t)((SLOT) > 49 ? 49 : (SLOT)) * 16384;\
            bf[BUF][0] = *reinterpret_cast<const b16x8*>(p_);                  \
            bf[BUF][1] = *reinterpret_cast<const b16x8*>(p_ + 1024);           \
        }

    // prologue
    LOADB(0, 0)
    LOADB(1, 1)
    stage_u(0);
    stage_u(1);
    __syncthreads();               // su_sh stable from here on; no more barriers

    #pragma unroll
    for (int g = 0; g < 5; ++g) {                  // g == kw (fully unrolled)
        const int hx   = col + g;
        const int coff = hx * 32 + ((xg ^ ((hx >> 1) & 3)) * 8);
        #pragma unroll
        for (int ks = 0; ks < 2; ++ks) {
            const unsigned short* apb =
                su_sh + ks * 12800 + ybase * 640 + coff;

            // init circular A-window (u-frags): rows 0..7 relative to ybase
            b16x8 aw[8];
            #pragma unroll
            for (int i = 0; i < 8; ++i)
                aw[i] = *reinterpret_cast<const b16x8*>(apb + i * 640);

            #pragma unroll
            for (int kh = 0; kh < 5; ++kh) {
                const int l = g * 10 + ks * 5 + kh;     // compile-time

                LOADB(l + 2, (l + 2) % 3)               // distance-2 prefetch

                __builtin_amdgcn_s_setprio(1);
                #pragma unroll
                for (int f = 0; f < 8; ++f) {
                    // SWAPPED: A = weights (lane&15 = od), B = u (lane&15 = x)
                    acc[f][0] = __builtin_amdgcn_mfma_f32_16x16x32_bf16(
                        bf[l % 3][0], aw[(kh + f) & 7], acc[f][0], 0, 0, 0);
                    acc[f][1] = __builtin_amdgcn_mfma_f32_16x16x32_bf16(
                        bf[l % 3][1], aw[(kh + f) & 7], acc[f][1], 0, 0, 0);
                }
                __builtin_amdgcn_s_setprio(0);

                if (kh < 4)                             // slide AFTER cluster
                    aw[kh & 7] = *reinterpret_cast<const b16x8*>(
                        apb + (kh + 8) * 640);
            }
        }
    }
    #undef LOADB

    // ---- epilogue: bias + r-scale + squash (in-lane + 2 shfl) + stores ----
    // C layout: value(y=ybase+f, x=tx0+col, od=fr*16+xg*4+r)
    float4 bb0 = *reinterpret_cast<const float4*>(wsb + wn * 32 + xg * 4);
    float4 bb1 = *reinterpret_cast<const float4*>(wsb + wn * 32 + 16 + xg * 4);

    const int x = tx0 + col;
    const int colsv = min(x + 2, 127) - max(x - 2, 0) + 1;
    float* pout = out + ((size_t)(b * 8 + wn) * 32 + xg * 4) * 16384 + x;

    #pragma unroll
    for (int f = 0; f < 8; ++f) {
        int h = ty0 + ybase + f;
        int rows = min(h + 2, 127) - max(h - 2, 0) + 1;
        float rs = 1.0f / (8.0f * (float)(rows * colsv));
        float p[8];
        float sq = 0.f;
        #pragma unroll
        for (int r = 0; r < 4; ++r) {
            float v0 = (acc[f][0][r] + bb0[r]) * rs;
            float v1 = (acc[f][1][r] + bb1[r]) * rs;
            p[r] = v0; p[4 + r] = v1;
            sq += v0 * v0;
            sq += v1 * v1;
        }
        sq += __shfl_xor(sq, 16);
        sq += __shfl_xor(sq, 32);
        float scale = sq / ((1.0f + sq) * sqrtf(sq + 1e-9f));
        float* ph = pout + (size_t)h * 128;
        #pragma unroll
        for (int r = 0; r < 4; ++r) {
            ph[(size_t)r * 16384]        = p[r] * scale;      // od = xg*4+r
            ph[(size_t)(16 + r) * 16384] = p[4 + r] * scale;  // od = 16+xg*4+r
        }
    }
}

extern "C" void kernel_launch(void* const* d_in, const int* in_sizes, int n_in,
                              void* d_out, int out_size, void* d_ws, size_t ws_size,
                              hipStream_t stream) {
    const float* u    = (const float*)d_in[0];
    const float* Wt   = (const float*)d_in[1];
    const float* bias = (const float*)d_in[2];
    unsigned short* wsw = (unsigned short*)d_ws;
    float* wsb = (float*)((char*)d_ws + 819200);

    repack_w<<<1601, 256, 0, stream>>>(Wt, bias, wsw, wsb);
    caps_mfma<<<dim3(64, 4), 1024, 0, stream>>>(u, wsw, wsb, (float*)d_out);
}

// Round 19
// 58.249 us; speedup vs baseline: 1.1986x; 1.0131x over previous
//
#include <hip/hip_runtime.h>
#include <math.h>

typedef __attribute__((ext_vector_type(8))) __bf16 b16x8;
typedef __attribute__((ext_vector_type(4))) float f32x4;
typedef __attribute__((ext_vector_type(8))) unsigned short u16x8;

__device__ __forceinline__ unsigned short f2bf(float x) {
    unsigned int v = __float_as_uint(x);
    v += 0x7fffu + ((v >> 16) & 1u);
    return (unsigned short)(v >> 16);
}

// ---------------- repack kernel ----------------
// ws: [0, 819200): weights bf16, PER-WAVE-CONTIGUOUS, visit order:
//   slot l = kw*10 + ks*5 + kh   (conv tap = kh*5+kw, cin plane ks)
//   byte = l*16384 + wn*2048 + fr*1024 + lane*16
//   value = W[cin = ks*32 + (lane>>4)*8 + j][o = wn*32 + fr*16 + (lane&15)]
// One thread per 8-j group: 8 strided loads -> one ushort8 store.
// [819200, 820224): bias_sum fp32 [256]
__global__ __launch_bounds__(256) void repack_w(
    const float* __restrict__ Wt, const float* __restrict__ bias,
    unsigned short* __restrict__ wsw, float* __restrict__ wsb) {
    int idx = blockIdx.x * 256 + threadIdx.x;   // 0..51455
    if (idx < 51200) {
        int lane = idx & 63;
        int fr   = (idx >> 6) & 1;
        int wn   = (idx >> 7) & 7;
        int l    = idx >> 10;          // visit slot 0..49
        int kh   = l % 5;
        int ks   = (l / 5) & 1;
        int kw   = l / 10;
        int tap  = kh * 5 + kw;
        int col  = lane & 15;
        int cg   = lane >> 4;
        int o    = wn * 32 + fr * 16 + col;
        int ic   = ks * 2 + (cg >> 1);          // cin>>4 (j-independent)
        int id0  = (cg & 1) * 8;                // cin&15 base
        const float* wb = Wt + (size_t)(ic * 256 + o) * 16 * 25 + tap;
        u16x8 v;
        #pragma unroll
        for (int j = 0; j < 8; ++j)
            v[j] = f2bf(wb[(size_t)(id0 + j) * 25]);
        *reinterpret_cast<u16x8*>(wsw + (size_t)idx * 8) = v;
    } else if (idx < 51456) {
        int o = idx - 51200;
        float s = 0.f;
        for (int ic = 0; ic < 4; ++ic) s += bias[ic * 256 + o];
        wsb[o] = s;
    }
}

// ---------------- main kernel ---------------- (R15 loop, fused prologue)
// Block: 1024 threads (16 waves) = one 16x16 spatial tile x all 256 outputs;
// grid 64x4 = 256 blocks = 1/CU. Wave = 128px x 32out, zero barriers after
// the prologue.
//  - SWAPPED MFMA operands: acc = mfma(W_frag, u_frag, acc) -> C col = pixel
//    x, row = od; squash = 8 in-lane + shfl_xor(16)+shfl_xor(32); stores
//    contiguous per xg group.
//  - B (weights): distance-2 register prefetch, 3 buffers, compile-time %3
//    rotation (g-loop fully unrolled), straight from L2 (2KB/wave/slot).
//  - A (u): circular 8-row register window per (kw,ks); slide AFTER the
//    MFMA cluster (post-cluster write keeps the live row intact).
//  - Prologue fused: one index decomposition per {2 cin-planes x hx-pair}
//    (pair shares the XOR-swizzle group) -> 6.25 iters/thread vs 25,
//    divides cut 4x. Same LDS bytes as R15.
__global__ __launch_bounds__(1024, 4) void caps_mfma(
    const float* __restrict__ u, const unsigned short* __restrict__ wsw,
    const float* __restrict__ wsb, float* __restrict__ out) {

    __shared__ __align__(16) unsigned short su_sh[25600];   // 2 planes x [hy20][hx20][cgp4][j8]

    const int tid  = threadIdx.x;
    const int lane = tid & 63;
    const int wid  = tid >> 6;      // 0..15
    const int wm   = wid >> 3;      // 0..1  pixel-row-group (8 rows each)
    const int wn   = wid & 7;       // 0..7  capsule (32 outs each)
    const int col  = lane & 15;
    const int xg   = lane >> 4;     // 0..3
    const int ybase = wm * 8;

    const int bx  = blockIdx.x;     // 0..63
    const int b   = blockIdx.y;     // 0..3
    const int ty0 = (bx >> 3) * 16;
    const int tx0 = (bx & 7) * 16;

    f32x4 acc[8][2];
    #pragma unroll
    for (int f = 0; f < 8; ++f) {
        acc[f][0] = (f32x4)0.f;
        acc[f][1] = (f32x4)0.f;
    }

    // per-wave weight base: slot stride 16384B, [wn]2048B, [fr]1024B, lane*16B
    const char* wp0 = ((const char*)wsw) + wn * 2048 + lane * 16;

    // B triple buffer (distance-2 prefetch), rotated at compile time
    b16x8 bf[3][2];
    #define LOADB(SLOT, BUF)                                                   \
        {                                                                      \
            const char* p_ = wp0 + (size_t)((SLOT) > 49 ? 49 : (SLOT)) * 16384;\
            bf[BUF][0] = *reinterpret_cast<const b16x8*>(p_);                  \
            bf[BUF][1] = *reinterpret_cast<const b16x8*>(p_ + 1024);           \
        }

    // prologue: weight slots 0,1 + fused u halo stage (both planes)
    LOADB(0, 0)
    LOADB(1, 1)
    {
        const float* up = u + (size_t)b * 64 * 16384;
        #pragma unroll 1
        for (int i = tid; i < 6400; i += 1024) {
            int c  = i / 200;                   // cin local 0..31
            int s  = i - c * 200;
            int hy = s / 10;                    // halo row 0..19
            int hp = (s - hy * 10) * 2;         // hx pair base: 0,2,...,18
            int gy = ty0 - 2 + hy;
            int gx0 = tx0 - 2 + hp;
            float v00 = 0.f, v01 = 0.f, v10 = 0.f, v11 = 0.f;
            if ((unsigned)gy < 128u) {
                const float* p0 = up + (size_t)c * 16384 + (size_t)gy * 128;
                const float* p1 = p0 + (size_t)32 * 16384;
                if ((unsigned)gx0 < 128u)       { v00 = p0[gx0];     v10 = p1[gx0];     }
                if ((unsigned)(gx0 + 1) < 128u) { v01 = p0[gx0 + 1]; v11 = p1[gx0 + 1]; }
            }
            int cgp = (c >> 3) ^ ((hp >> 1) & 3);   // shared by the hx pair
            int off = (hy * 20 + hp) * 32 + cgp * 8 + (c & 7);
            su_sh[off]         = f2bf(v00);
            su_sh[off + 32]    = f2bf(v01);
            su_sh[off + 12800] = f2bf(v10);
            su_sh[off + 12832] = f2bf(v11);
        }
    }
    __syncthreads();               // su_sh stable from here on; no more barriers

    #pragma unroll
    for (int g = 0; g < 5; ++g) {                  // g == kw (fully unrolled)
        const int hx   = col + g;
        const int coff = hx * 32 + ((xg ^ ((hx >> 1) & 3)) * 8);
        #pragma unroll
        for (int ks = 0; ks < 2; ++ks) {
            const unsigned short* apb =
                su_sh + ks * 12800 + ybase * 640 + coff;

            // init circular A-window (u-frags): rows 0..7 relative to ybase
            b16x8 aw[8];
            #pragma unroll
            for (int i = 0; i < 8; ++i)
                aw[i] = *reinterpret_cast<const b16x8*>(apb + i * 640);

            #pragma unroll
            for (int kh = 0; kh < 5; ++kh) {
                const int l = g * 10 + ks * 5 + kh;     // compile-time

                LOADB(l + 2, (l + 2) % 3)               // distance-2 prefetch

                __builtin_amdgcn_s_setprio(1);
                #pragma unroll
                for (int f = 0; f < 8; ++f) {
                    // SWAPPED: A = weights (lane&15 = od), B = u (lane&15 = x)
                    acc[f][0] = __builtin_amdgcn_mfma_f32_16x16x32_bf16(
                        bf[l % 3][0], aw[(kh + f) & 7], acc[f][0], 0, 0, 0);
                    acc[f][1] = __builtin_amdgcn_mfma_f32_16x16x32_bf16(
                        bf[l % 3][1], aw[(kh + f) & 7], acc[f][1], 0, 0, 0);
                }
                __builtin_amdgcn_s_setprio(0);

                if (kh < 4)                             // slide AFTER cluster
                    aw[kh & 7] = *reinterpret_cast<const b16x8*>(
                        apb + (kh + 8) * 640);
            }
        }
    }
    #undef LOADB

    // ---- epilogue: bias + r-scale + squash (in-lane + 2 shfl) + stores ----
    // C layout: value(y=ybase+f, x=tx0+col, od=fr*16+xg*4+r)
    float4 bb0 = *reinterpret_cast<const float4*>(wsb + wn * 32 + xg * 4);
    float4 bb1 = *reinterpret_cast<const float4*>(wsb + wn * 32 + 16 + xg * 4);

    const int x = tx0 + col;
    const int colsv = min(x + 2, 127) - max(x - 2, 0) + 1;
    float* pout = out + ((size_t)(b * 8 + wn) * 32 + xg * 4) * 16384 + x;

    #pragma unroll
    for (int f = 0; f < 8; ++f) {
        int h = ty0 + ybase + f;
        int rows = min(h + 2, 127) - max(h - 2, 0) + 1;
        float rs = 1.0f / (8.0f * (float)(rows * colsv));
        float p[8];
        float sq = 0.f;
        #pragma unroll
        for (int r = 0; r < 4; ++r) {
            float v0 = (acc[f][0][r] + bb0[r]) * rs;
            float v1 = (acc[f][1][r] + bb1[r]) * rs;
            p[r] = v0; p[4 + r] = v1;
            sq += v0 * v0;
            sq += v1 * v1;
        }
        sq += __shfl_xor(sq, 16);
        sq += __shfl_xor(sq, 32);
        float scale = sq / ((1.0f + sq) * sqrtf(sq + 1e-9f));
        float* ph = pout + (size_t)h * 128;
        #pragma unroll
        for (int r = 0; r < 4; ++r) {
            ph[(size_t)r * 16384]        = p[r] * scale;      // od = xg*4+r
            ph[(size_t)(16 + r) * 16384] = p[4 + r] * scale;  // od = 16+xg*4+r
        }
    }
}

extern "C" void kernel_launch(void* const* d_in, const int* in_sizes, int n_in,
                              void* d_out, int out_size, void* d_ws, size_t ws_size,
                              hipStream_t stream) {
    const float* u    = (const float*)d_in[0];
    const float* Wt   = (const float*)d_in[1];
    const float* bias = (const float*)d_in[2];
    unsigned short* wsw = (unsigned short*)d_ws;
    float* wsb = (float*)((char*)d_ws + 819200);

    repack_w<<<201, 256, 0, stream>>>(Wt, bias, wsw, wsb);
    caps_mfma<<<dim3(64, 4), 1024, 0, stream>>>(u, wsw, wsb, (float*)d_out);
}